// Round 1
// baseline (11805.494 us; speedup 1.0000x reference)
//
#include <hip/hip_runtime.h>
#include <math.h>

#define NN 20000
#define NE 640000
#define C 128
#define DE 64
#define ZD 320
#define HD 512
#define G 32
#define LL 3
#define EPSV 1e-5f

// ---------------- graph counting ----------------
__global__ __launch_bounds__(256) void k_gcount(const int* __restrict__ nb, int* __restrict__ gcount) {
    int i = blockIdx.x * 256 + threadIdx.x;
    if (i < NN) atomicAdd(&gcount[nb[i]], 1);
}

// ---------------- CGConv edge kernel ----------------
// 16 edges/block, gather z=[x[dst],x[src],ea] into LDS, dual fp32 GEMM (gate+core),
// sigmoid*softplus, atomic scatter-add into xnew (pre-initialized with x).
__global__ __launch_bounds__(256) void k_edge(
    const float* __restrict__ x, const int* __restrict__ ei,
    const float* __restrict__ ea, const float* __restrict__ Wf,
    const float* __restrict__ bf, const float* __restrict__ Ws,
    const float* __restrict__ bs, float* __restrict__ xnew)
{
    __shared__ float zt[16 * 324];
    __shared__ int s_src[16], s_dst[16];
    const int tid = threadIdx.x;
    const int e0 = blockIdx.x * 16;
    if (tid < 16) s_src[tid] = ei[e0 + tid];
    else if (tid < 32) s_dst[tid - 16] = ei[NE + e0 + (tid - 16)];
    __syncthreads();

    // gather: 16 edges x 80 float4 = 1280 float4, 5 per thread
    for (int it = 0; it < 5; ++it) {
        int idx = tid + it * 256;
        int e = idx / 80;
        int c = (idx - e * 80) * 4;
        float4 v;
        if (c < 128)      v = *(const float4*)(x + (size_t)s_dst[e] * C + c);
        else if (c < 256) v = *(const float4*)(x + (size_t)s_src[e] * C + (c - 128));
        else              v = *(const float4*)(ea + (size_t)(e0 + e) * DE + (c - 256));
        *(float4*)(zt + e * 324 + c) = v;
    }
    __syncthreads();

    const int ch = tid & 127;
    const int eb = (tid >> 7) * 8;
    float accf[8], accs[8];
#pragma unroll
    for (int j = 0; j < 8; ++j) { accf[j] = 0.f; accs[j] = 0.f; }
    const float4* wfr = (const float4*)(Wf + (size_t)ch * ZD);
    const float4* wsr = (const float4*)(Ws + (size_t)ch * ZD);
    for (int k4 = 0; k4 < 80; ++k4) {
        float4 wf = wfr[k4];
        float4 wv = wsr[k4];
#pragma unroll
        for (int j = 0; j < 8; ++j) {
            float4 z = *(const float4*)(zt + (eb + j) * 324 + k4 * 4);
            accf[j] = fmaf(z.x, wf.x, accf[j]);
            accf[j] = fmaf(z.y, wf.y, accf[j]);
            accf[j] = fmaf(z.z, wf.z, accf[j]);
            accf[j] = fmaf(z.w, wf.w, accf[j]);
            accs[j] = fmaf(z.x, wv.x, accs[j]);
            accs[j] = fmaf(z.y, wv.y, accs[j]);
            accs[j] = fmaf(z.z, wv.z, accs[j]);
            accs[j] = fmaf(z.w, wv.w, accs[j]);
        }
    }
    const float bfv = bf[ch], bsv = bs[ch];
#pragma unroll
    for (int j = 0; j < 8; ++j) {
        float gv = accf[j] + bfv;
        float sv = accs[j] + bsv;
        float gate = 1.0f / (1.0f + expf(-gv));
        float sp = fmaxf(sv, 0.0f) + log1pf(expf(-fabsf(sv)));
        unsafeAtomicAdd(xnew + (size_t)s_dst[eb + j] * C + ch, gate * sp);
    }
}

// ---------------- MLP GEMM1: h = x @ W1^T + b1, plus column stats ----------------
__global__ __launch_bounds__(256) void k_mlp1(
    const float* __restrict__ x, const float* __restrict__ W1, const float* __restrict__ b1,
    float* __restrict__ h, float* __restrict__ colsum, float* __restrict__ colsq)
{
    __shared__ float xs[16 * 132];
    __shared__ float red[2][256];
    const int tid = threadIdx.x;
    const int n0 = blockIdx.x * 16;
    const int ch0 = blockIdx.y * 64;
#pragma unroll
    for (int it = 0; it < 2; ++it) {
        int idx = tid + it * 256;       // 512 float4 total
        int n = idx >> 5;               // 32 float4 per row
        int c = (idx & 31) * 4;
        float4 v = *(const float4*)(x + (size_t)(n0 + n) * C + c);
        *(float4*)(xs + n * 132 + c) = v;
    }
    __syncthreads();
    const int chl = tid & 63, nb = tid >> 6;
    const int ch = ch0 + chl;
    const float4* wr = (const float4*)(W1 + (size_t)ch * C);
    float acc[4] = {0.f, 0.f, 0.f, 0.f};
    for (int k4 = 0; k4 < 32; ++k4) {
        float4 w = wr[k4];
#pragma unroll
        for (int j = 0; j < 4; ++j) {
            float4 xv = *(const float4*)(xs + (nb + 4 * j) * 132 + k4 * 4);
            acc[j] = fmaf(xv.x, w.x, acc[j]);
            acc[j] = fmaf(xv.y, w.y, acc[j]);
            acc[j] = fmaf(xv.z, w.z, acc[j]);
            acc[j] = fmaf(xv.w, w.w, acc[j]);
        }
    }
    const float bv = b1[ch];
    float ps = 0.f, pq = 0.f;
#pragma unroll
    for (int j = 0; j < 4; ++j) {
        float hv = acc[j] + bv;
        h[(size_t)(n0 + nb + 4 * j) * HD + ch] = hv;
        ps += hv; pq += hv * hv;
    }
    red[0][nb * 64 + chl] = ps;
    red[1][nb * 64 + chl] = pq;
    __syncthreads();
    if (tid < 64) {
        float s = 0.f, q = 0.f;
#pragma unroll
        for (int b = 0; b < 4; ++b) { s += red[0][b * 64 + tid]; q += red[1][b * 64 + tid]; }
        unsafeAtomicAdd(colsum + ch0 + tid, s);
        unsafeAtomicAdd(colsq + ch0 + tid, q);
    }
}

__global__ void k_bnstats(const float* __restrict__ colsum, const float* __restrict__ colsq,
                          float* __restrict__ mu, float* __restrict__ istd) {
    int c = threadIdx.x;
    float m = colsum[c] * (1.0f / NN);
    float v = colsq[c] * (1.0f / NN) - m * m;
    mu[c] = m;
    istd[c] = rsqrtf(fmaxf(v, 0.f) + EPSV);
}

// ---------------- MLP GEMM2: x2 = xres + relu(bn(h)) @ W2^T + b2 ----------------
__global__ __launch_bounds__(256) void k_mlp2(
    const float* __restrict__ h, const float* __restrict__ mu, const float* __restrict__ istd,
    const float* __restrict__ g1, const float* __restrict__ be1,
    const float* __restrict__ W2, const float* __restrict__ b2,
    const float* __restrict__ xres, float* __restrict__ xout)
{
    __shared__ float hs[16 * 516];
    const int tid = threadIdx.x;
    const int n0 = blockIdx.x * 16;
#pragma unroll
    for (int it = 0; it < 8; ++it) {
        int idx = tid + it * 256;       // 2048 float4 total
        int n = idx >> 7;               // 128 float4 per row
        int k = (idx & 127) * 4;
        float4 v = *(const float4*)(h + (size_t)(n0 + n) * HD + k);
        float4 m4 = *(const float4*)(mu + k);
        float4 s4 = *(const float4*)(istd + k);
        float4 g4 = *(const float4*)(g1 + k);
        float4 b4 = *(const float4*)(be1 + k);
        v.x = fmaxf(fmaf(g4.x * s4.x, v.x - m4.x, b4.x), 0.f);
        v.y = fmaxf(fmaf(g4.y * s4.y, v.y - m4.y, b4.y), 0.f);
        v.z = fmaxf(fmaf(g4.z * s4.z, v.z - m4.z, b4.z), 0.f);
        v.w = fmaxf(fmaf(g4.w * s4.w, v.w - m4.w, b4.w), 0.f);
        *(float4*)(hs + n * 516 + k) = v;
    }
    __syncthreads();
    const int ch = tid & 127, nb = tid >> 7;
    const float4* wr = (const float4*)(W2 + (size_t)ch * HD);
    float acc[8];
#pragma unroll
    for (int j = 0; j < 8; ++j) acc[j] = 0.f;
    for (int k4 = 0; k4 < 128; ++k4) {
        float4 w = wr[k4];
#pragma unroll
        for (int j = 0; j < 8; ++j) {
            float4 hv = *(const float4*)(hs + (nb + 2 * j) * 516 + k4 * 4);
            acc[j] = fmaf(hv.x, w.x, acc[j]);
            acc[j] = fmaf(hv.y, w.y, acc[j]);
            acc[j] = fmaf(hv.z, w.z, acc[j]);
            acc[j] = fmaf(hv.w, w.w, acc[j]);
        }
    }
    const float bv = b2[ch];
#pragma unroll
    for (int j = 0; j < 8; ++j) {
        int n = n0 + nb + 2 * j;
        xout[(size_t)n * C + ch] = xres[(size_t)n * C + ch] + acc[j] + bv;
    }
}

// ---------------- graph LayerNorm ----------------
__global__ __launch_bounds__(256) void k_lnstats(
    const float* __restrict__ x2, const int* __restrict__ nb_arr,
    float* __restrict__ gsum, float* __restrict__ gsq)
{
    const int tid = threadIdx.x;
    const int node = blockIdx.x * 64 + (tid >> 2);
    const int sub = tid & 3;
    if (node >= NN) return;
    const float4* row = (const float4*)(x2 + (size_t)node * C);
    float s = 0.f, q = 0.f;
#pragma unroll
    for (int t = 0; t < 8; ++t) {
        float4 v = row[sub + 4 * t];
        s += v.x + v.y + v.z + v.w;
        q += v.x * v.x + v.y * v.y + v.z * v.z + v.w * v.w;
    }
    s += __shfl_xor(s, 1); q += __shfl_xor(q, 1);
    s += __shfl_xor(s, 2); q += __shfl_xor(q, 2);
    if (sub == 0) {
        int g = nb_arr[node];
        unsafeAtomicAdd(&gsum[g], s);
        unsafeAtomicAdd(&gsq[g], q);
    }
}

__global__ void k_lnfin(const float* __restrict__ gsum, const float* __restrict__ gsq,
                        const int* __restrict__ gcount,
                        float* __restrict__ gmean, float* __restrict__ gistd) {
    int g = threadIdx.x;
    float cnt = fmaxf((float)gcount[g], 1.0f) * (float)C;
    float m = gsum[g] / cnt;
    float v = gsq[g] / cnt - m * m;
    gmean[g] = m;
    gistd[g] = rsqrtf(fmaxf(v, 0.f) + EPSV);
}

__global__ __launch_bounds__(256) void k_lnapply(
    const float* __restrict__ x2, const int* __restrict__ nb_arr,
    const float* __restrict__ gmean, const float* __restrict__ gistd,
    const float* __restrict__ lnw, const float* __restrict__ lnb, float* __restrict__ out)
{
    int idx = blockIdx.x * 256 + threadIdx.x;   // N*C = 2,560,000 exactly
    int n = idx >> 7, c = idx & 127;
    int g = nb_arr[n];
    out[idx] = (x2[idx] - gmean[g]) * gistd[g] * lnw[c] + lnb[c];
}

// ---------------- launcher ----------------
extern "C" void kernel_launch(void* const* d_in, const int* in_sizes, int n_in,
                              void* d_out, int out_size, void* d_ws, size_t ws_size,
                              hipStream_t stream) {
    const float* x_in = (const float*)d_in[0];
    const int* node_batch = (const int*)d_in[1];
    const int* ei = (const int*)d_in[2];
    const float* ea = (const float*)d_in[3];
    const float* Wf = (const float*)d_in[4];
    const float* bf = (const float*)d_in[5];
    const float* Ws = (const float*)d_in[6];
    const float* bs = (const float*)d_in[7];
    const float* W1 = (const float*)d_in[8];
    const float* b1 = (const float*)d_in[9];
    const float* g1 = (const float*)d_in[10];
    const float* be1 = (const float*)d_in[11];
    const float* W2 = (const float*)d_in[12];
    const float* b2 = (const float*)d_in[13];
    const float* lnw = (const float*)d_in[14];
    const float* lnb = (const float*)d_in[15];
    float* out = (float*)d_out;

    const size_t NC = (size_t)NN * C;       // 2,560,000
    const size_t NH = (size_t)NN * HD;      // 10,240,000
    float* ws = (float*)d_ws;
    float* xa = ws;
    float* xb = ws + NC;
    float* h = ws + 2 * NC;
    float* st = ws + 2 * NC + NH;
    float* colsum = st;
    float* colsq = st + 512;
    float* mu = st + 1024;
    float* istd = st + 1536;
    float* gsum = st + 2048;
    float* gsq = st + 2080;
    float* gmean = st + 2112;
    float* gistd = st + 2144;
    int* gcount = (int*)(st + 2176);

    hipMemcpyAsync(xa, x_in, NC * 4, hipMemcpyDeviceToDevice, stream);
    hipMemsetAsync(gcount, 0, G * 4, stream);
    k_gcount<<<(NN + 255) / 256, 256, 0, stream>>>(node_batch, gcount);

    for (int l = 0; l < LL; ++l) {
        hipMemcpyAsync(xb, xa, NC * 4, hipMemcpyDeviceToDevice, stream);
        k_edge<<<NE / 16, 256, 0, stream>>>(xa, ei, ea,
            Wf + (size_t)l * C * ZD, bf + (size_t)l * C,
            Ws + (size_t)l * C * ZD, bs + (size_t)l * C, xb);

        hipMemsetAsync(colsum, 0, 1024 * 4, stream);
        k_mlp1<<<dim3(NN / 16, HD / 64), 256, 0, stream>>>(xb,
            W1 + (size_t)l * HD * C, b1 + (size_t)l * HD, h, colsum, colsq);
        k_bnstats<<<1, HD, 0, stream>>>(colsum, colsq, mu, istd);

        hipMemsetAsync(gsum, 0, 64 * 4, stream);
        k_mlp2<<<NN / 16, 256, 0, stream>>>(h, mu, istd,
            g1 + (size_t)l * HD, be1 + (size_t)l * HD,
            W2 + (size_t)l * C * HD, b2 + (size_t)l * C, xb, xa);

        k_lnstats<<<(NN + 63) / 64, 256, 0, stream>>>(xa, node_batch, gsum, gsq);
        k_lnfin<<<1, G, 0, stream>>>(gsum, gsq, gcount, gmean, gistd);
        float* dstp = (l == LL - 1) ? out : xa;
        k_lnapply<<<(NN * C) / 256, 256, 0, stream>>>(xa, node_batch, gmean, gistd,
            lnw + (size_t)l * C, lnb + (size_t)l * C, dstp);
    }
}

// Round 2
// 3049.437 us; speedup vs baseline: 3.8714x; 3.8714x over previous
//
#include <hip/hip_runtime.h>
#include <hip/hip_bf16.h>
#include <math.h>

#define NN 20000
#define NE 640000
#define C 128
#define DE 64
#define ZD 320
#define HD 512
#define G 32
#define LL 3
#define EPSV 1e-5f

typedef __attribute__((ext_vector_type(8))) short bf16x8;
typedef __attribute__((ext_vector_type(4))) float f32x4;

__device__ __forceinline__ ushort f2bf(float f) {
    __hip_bfloat16 h = __float2bfloat16(f);
    return *reinterpret_cast<ushort*>(&h);
}

// ---------------- graph counting ----------------
__global__ __launch_bounds__(256) void k_gcount(const int* __restrict__ nb, int* __restrict__ gcount) {
    int i = blockIdx.x * 256 + threadIdx.x;
    if (i < NN) atomicAdd(&gcount[nb[i]], 1);
}

// ---------------- cast x -> bf16 ----------------
__global__ __launch_bounds__(256) void k_cast_x(const float* __restrict__ in, ushort* __restrict__ out) {
    int idx = blockIdx.x * 256 + threadIdx.x;    // NN*C/4 = 640000 threads
    float4 v = ((const float4*)in)[idx];
    ushort4 o;
    o.x = f2bf(v.x); o.y = f2bf(v.y); o.z = f2bf(v.z); o.w = f2bf(v.w);
    ((ushort4*)out)[idx] = o;
}

// ---------------- build combined bf16 weights ----------------
// Combined row r (0..255): w=r>>6, j=(r>>4)&3, off=r&15; ch = w*32 + (j&1)*16 + off.
// j<2 -> gate (Wf), j>=2 -> softplus (Ws). Wave w's col-tiles j=0,1 are gate for
// channels [w*32, w*32+32), j=2,3 the matching softplus channels.
__global__ __launch_bounds__(256) void k_prepw(
    const float* __restrict__ Wf, const float* __restrict__ bfv,
    const float* __restrict__ Ws, const float* __restrict__ bsv,
    ushort* __restrict__ Wc, float* __restrict__ bc)
{
    int idx = blockIdx.x * 256 + threadIdx.x;    // 256*320 = 81920
    int r = idx / 320, k = idx - r * 320;
    int w = r >> 6, j = (r >> 4) & 3, off = r & 15;
    int ch = w * 32 + (j & 1) * 16 + off;
    const float* W = (j < 2) ? Wf : Ws;
    Wc[idx] = f2bf(W[(size_t)ch * ZD + k]);
    if (k == 0) bc[r] = ((j < 2) ? bfv : bsv)[ch];
}

// ---------------- CGConv edge kernel (MFMA) ----------------
// 64 edges/block, 4 waves. z[64][320] bf16 in LDS (row stride 328).
// Wave w computes all 4 row-tiles x its 4 col-tiles (64 combined channels).
__global__ __launch_bounds__(256) void k_edge_mfma(
    const ushort* __restrict__ x16, const int* __restrict__ ei,
    const float* __restrict__ ea, const ushort* __restrict__ Wc,
    const float* __restrict__ bc, float* __restrict__ xnew)
{
    __shared__ ushort zt[64][328];
    __shared__ int s_src[64], s_dst[64];
    const int tid = threadIdx.x;
    const int e0 = blockIdx.x * 64;
    if (tid < 64) s_src[tid] = ei[e0 + tid];
    else if (tid < 128) s_dst[tid - 64] = ei[NE + e0 + (tid - 64)];
    __syncthreads();

    // gather: 64 edges x 40 chunks (8 bf16 each) = 2560 chunks, 10 per thread
    for (int it = 0; it < 10; ++it) {
        int idx = tid + it * 256;
        int e = idx / 40;
        int r = idx - e * 40;
        if (r < 32) {
            const ushort* s = (r < 16)
                ? x16 + (size_t)s_dst[e] * C + r * 8
                : x16 + (size_t)s_src[e] * C + (r - 16) * 8;
            *(uint4*)(&zt[e][r * 8]) = *(const uint4*)s;
        } else {
            const float* s = ea + (size_t)(e0 + e) * DE + (r - 32) * 8;
            float4 u = *(const float4*)s;
            float4 v = *(const float4*)(s + 4);
            ushort4 o0, o1;
            o0.x = f2bf(u.x); o0.y = f2bf(u.y); o0.z = f2bf(u.z); o0.w = f2bf(u.w);
            o1.x = f2bf(v.x); o1.y = f2bf(v.y); o1.z = f2bf(v.z); o1.w = f2bf(v.w);
            *(ushort4*)(&zt[e][r * 8]) = o0;
            *(ushort4*)(&zt[e][r * 8 + 4]) = o1;
        }
    }
    __syncthreads();

    const int w = tid >> 6, l = tid & 63;
    const int lr = l & 15;
    const int kp = (l >> 4) * 8;
    f32x4 acc[4][4];
#pragma unroll
    for (int rt = 0; rt < 4; ++rt)
#pragma unroll
        for (int j = 0; j < 4; ++j) acc[rt][j] = (f32x4){0.f, 0.f, 0.f, 0.f};

    for (int kk = 0; kk < 10; ++kk) {
        const int k0 = kk * 32 + kp;
        bf16x8 a[4], b[4];
#pragma unroll
        for (int rt = 0; rt < 4; ++rt)
            a[rt] = *(const bf16x8*)(&zt[rt * 16 + lr][k0]);
#pragma unroll
        for (int j = 0; j < 4; ++j) {
            int row = (w * 4 + j) * 16 + lr;
            b[j] = *(const bf16x8*)(Wc + (size_t)row * ZD + k0);
        }
#pragma unroll
        for (int rt = 0; rt < 4; ++rt)
#pragma unroll
            for (int j = 0; j < 4; ++j)
                acc[rt][j] = __builtin_amdgcn_mfma_f32_16x16x32_bf16(a[rt], b[j], acc[rt][j], 0, 0, 0);
    }

    // epilogue: lane holds D[row=(l>>4)*4+q][col=lr] per tile
    const int ro = (l >> 4) * 4;
    const float bg0 = bc[w * 64 + lr];
    const float bg1 = bc[w * 64 + 16 + lr];
    const float bs0 = bc[w * 64 + 32 + lr];
    const float bs1 = bc[w * 64 + 48 + lr];
#pragma unroll
    for (int rt = 0; rt < 4; ++rt) {
#pragma unroll
        for (int j2 = 0; j2 < 2; ++j2) {
            const int ch = w * 32 + j2 * 16 + lr;
            const float bg = j2 ? bg1 : bg0;
            const float bs = j2 ? bs1 : bs0;
#pragma unroll
            for (int q = 0; q < 4; ++q) {
                int e = rt * 16 + ro + q;
                float g = acc[rt][j2][q] + bg;
                float s = acc[rt][j2 + 2][q] + bs;
                float gate = 1.0f / (1.0f + expf(-g));
                float sp = fmaxf(s, 0.0f) + log1pf(expf(-fabsf(s)));
                unsafeAtomicAdd(xnew + (size_t)s_dst[e] * C + ch, gate * sp);
            }
        }
    }
}

// ---------------- MLP GEMM1: h = x @ W1^T + b1, plus column stats ----------------
__global__ __launch_bounds__(256) void k_mlp1(
    const float* __restrict__ x, const float* __restrict__ W1, const float* __restrict__ b1,
    float* __restrict__ h, float* __restrict__ colsum, float* __restrict__ colsq)
{
    __shared__ float xs[16 * 132];
    __shared__ float red[2][256];
    const int tid = threadIdx.x;
    const int n0 = blockIdx.x * 16;
    const int ch0 = blockIdx.y * 64;
#pragma unroll
    for (int it = 0; it < 2; ++it) {
        int idx = tid + it * 256;
        int n = idx >> 5;
        int c = (idx & 31) * 4;
        float4 v = *(const float4*)(x + (size_t)(n0 + n) * C + c);
        *(float4*)(xs + n * 132 + c) = v;
    }
    __syncthreads();
    const int chl = tid & 63, nb = tid >> 6;
    const int ch = ch0 + chl;
    const float4* wr = (const float4*)(W1 + (size_t)ch * C);
    float acc[4] = {0.f, 0.f, 0.f, 0.f};
    for (int k4 = 0; k4 < 32; ++k4) {
        float4 w = wr[k4];
#pragma unroll
        for (int j = 0; j < 4; ++j) {
            float4 xv = *(const float4*)(xs + (nb + 4 * j) * 132 + k4 * 4);
            acc[j] = fmaf(xv.x, w.x, acc[j]);
            acc[j] = fmaf(xv.y, w.y, acc[j]);
            acc[j] = fmaf(xv.z, w.z, acc[j]);
            acc[j] = fmaf(xv.w, w.w, acc[j]);
        }
    }
    const float bv = b1[ch];
    float ps = 0.f, pq = 0.f;
#pragma unroll
    for (int j = 0; j < 4; ++j) {
        float hv = acc[j] + bv;
        h[(size_t)(n0 + nb + 4 * j) * HD + ch] = hv;
        ps += hv; pq += hv * hv;
    }
    red[0][nb * 64 + chl] = ps;
    red[1][nb * 64 + chl] = pq;
    __syncthreads();
    if (tid < 64) {
        float s = 0.f, q = 0.f;
#pragma unroll
        for (int b = 0; b < 4; ++b) { s += red[0][b * 64 + tid]; q += red[1][b * 64 + tid]; }
        unsafeAtomicAdd(colsum + ch0 + tid, s);
        unsafeAtomicAdd(colsq + ch0 + tid, q);
    }
}

__global__ void k_bnstats(const float* __restrict__ colsum, const float* __restrict__ colsq,
                          float* __restrict__ mu, float* __restrict__ istd) {
    int c = threadIdx.x;
    float m = colsum[c] * (1.0f / NN);
    float v = colsq[c] * (1.0f / NN) - m * m;
    mu[c] = m;
    istd[c] = rsqrtf(fmaxf(v, 0.f) + EPSV);
}

// ---------------- MLP GEMM2: x2 = xres + relu(bn(h)) @ W2^T + b2 ----------------
__global__ __launch_bounds__(256) void k_mlp2(
    const float* __restrict__ h, const float* __restrict__ mu, const float* __restrict__ istd,
    const float* __restrict__ g1, const float* __restrict__ be1,
    const float* __restrict__ W2, const float* __restrict__ b2,
    const float* __restrict__ xres, float* __restrict__ xout)
{
    __shared__ float hs[16 * 516];
    const int tid = threadIdx.x;
    const int n0 = blockIdx.x * 16;
#pragma unroll
    for (int it = 0; it < 8; ++it) {
        int idx = tid + it * 256;
        int n = idx >> 7;
        int k = (idx & 127) * 4;
        float4 v = *(const float4*)(h + (size_t)(n0 + n) * HD + k);
        float4 m4 = *(const float4*)(mu + k);
        float4 s4 = *(const float4*)(istd + k);
        float4 g4 = *(const float4*)(g1 + k);
        float4 b4 = *(const float4*)(be1 + k);
        v.x = fmaxf(fmaf(g4.x * s4.x, v.x - m4.x, b4.x), 0.f);
        v.y = fmaxf(fmaf(g4.y * s4.y, v.y - m4.y, b4.y), 0.f);
        v.z = fmaxf(fmaf(g4.z * s4.z, v.z - m4.z, b4.z), 0.f);
        v.w = fmaxf(fmaf(g4.w * s4.w, v.w - m4.w, b4.w), 0.f);
        *(float4*)(hs + n * 516 + k) = v;
    }
    __syncthreads();
    const int ch = tid & 127, nb = tid >> 7;
    const float4* wr = (const float4*)(W2 + (size_t)ch * HD);
    float acc[8];
#pragma unroll
    for (int j = 0; j < 8; ++j) acc[j] = 0.f;
    for (int k4 = 0; k4 < 128; ++k4) {
        float4 w = wr[k4];
#pragma unroll
        for (int j = 0; j < 8; ++j) {
            float4 hv = *(const float4*)(hs + (nb + 2 * j) * 516 + k4 * 4);
            acc[j] = fmaf(hv.x, w.x, acc[j]);
            acc[j] = fmaf(hv.y, w.y, acc[j]);
            acc[j] = fmaf(hv.z, w.z, acc[j]);
            acc[j] = fmaf(hv.w, w.w, acc[j]);
        }
    }
    const float bv = b2[ch];
#pragma unroll
    for (int j = 0; j < 8; ++j) {
        int n = n0 + nb + 2 * j;
        xout[(size_t)n * C + ch] = xres[(size_t)n * C + ch] + acc[j] + bv;
    }
}

// ---------------- graph LayerNorm ----------------
__global__ __launch_bounds__(256) void k_lnstats(
    const float* __restrict__ x2, const int* __restrict__ nb_arr,
    float* __restrict__ gsum, float* __restrict__ gsq)
{
    const int tid = threadIdx.x;
    const int node = blockIdx.x * 64 + (tid >> 2);
    const int sub = tid & 3;
    if (node >= NN) return;
    const float4* row = (const float4*)(x2 + (size_t)node * C);
    float s = 0.f, q = 0.f;
#pragma unroll
    for (int t = 0; t < 8; ++t) {
        float4 v = row[sub + 4 * t];
        s += v.x + v.y + v.z + v.w;
        q += v.x * v.x + v.y * v.y + v.z * v.z + v.w * v.w;
    }
    s += __shfl_xor(s, 1); q += __shfl_xor(q, 1);
    s += __shfl_xor(s, 2); q += __shfl_xor(q, 2);
    if (sub == 0) {
        int g = nb_arr[node];
        unsafeAtomicAdd(&gsum[g], s);
        unsafeAtomicAdd(&gsq[g], q);
    }
}

__global__ void k_lnfin(const float* __restrict__ gsum, const float* __restrict__ gsq,
                        const int* __restrict__ gcount,
                        float* __restrict__ gmean, float* __restrict__ gistd) {
    int g = threadIdx.x;
    float cnt = fmaxf((float)gcount[g], 1.0f) * (float)C;
    float m = gsum[g] / cnt;
    float v = gsq[g] / cnt - m * m;
    gmean[g] = m;
    gistd[g] = rsqrtf(fmaxf(v, 0.f) + EPSV);
}

__global__ __launch_bounds__(256) void k_lnapply(
    const float* __restrict__ x2, const int* __restrict__ nb_arr,
    const float* __restrict__ gmean, const float* __restrict__ gistd,
    const float* __restrict__ lnw, const float* __restrict__ lnb, float* __restrict__ out)
{
    int idx = blockIdx.x * 256 + threadIdx.x;
    int n = idx >> 7, c = idx & 127;
    int g = nb_arr[n];
    out[idx] = (x2[idx] - gmean[g]) * gistd[g] * lnw[c] + lnb[c];
}

// ---------------- launcher ----------------
extern "C" void kernel_launch(void* const* d_in, const int* in_sizes, int n_in,
                              void* d_out, int out_size, void* d_ws, size_t ws_size,
                              hipStream_t stream) {
    const float* x_in = (const float*)d_in[0];
    const int* node_batch = (const int*)d_in[1];
    const int* ei = (const int*)d_in[2];
    const float* ea = (const float*)d_in[3];
    const float* Wf = (const float*)d_in[4];
    const float* bfv = (const float*)d_in[5];
    const float* Ws = (const float*)d_in[6];
    const float* bsv = (const float*)d_in[7];
    const float* W1 = (const float*)d_in[8];
    const float* b1 = (const float*)d_in[9];
    const float* g1 = (const float*)d_in[10];
    const float* be1 = (const float*)d_in[11];
    const float* W2 = (const float*)d_in[12];
    const float* b2 = (const float*)d_in[13];
    const float* lnw = (const float*)d_in[14];
    const float* lnb = (const float*)d_in[15];
    float* out = (float*)d_out;

    const size_t NC = (size_t)NN * C;       // 2,560,000
    const size_t NH = (size_t)NN * HD;      // 10,240,000
    float* ws = (float*)d_ws;
    float* xa = ws;
    float* xb = ws + NC;
    float* h = ws + 2 * NC;                 // NH floats; xb16 aliases its head
    float* st = ws + 2 * NC + NH;
    float* colsum = st;
    float* colsq = st + 512;
    float* mu = st + 1024;
    float* istd = st + 1536;
    float* gsum = st + 2048;
    float* gsq = st + 2080;
    float* gmean = st + 2112;
    float* gistd = st + 2144;
    int* gcount = (int*)(st + 2176);
    float* bc = st + 2304;                  // 256 floats
    ushort* Wc16 = (ushort*)(st + 2560);    // 81920 ushorts = 40960 floats
    ushort* xb16 = (ushort*)h;              // aliased: dead once k_mlp1 runs

    hipMemcpyAsync(xa, x_in, NC * 4, hipMemcpyDeviceToDevice, stream);
    hipMemsetAsync(gcount, 0, G * 4, stream);
    k_gcount<<<(NN + 255) / 256, 256, 0, stream>>>(node_batch, gcount);

    for (int l = 0; l < LL; ++l) {
        k_cast_x<<<NC / 1024, 256, 0, stream>>>(xa, xb16);
        k_prepw<<<320, 256, 0, stream>>>(
            Wf + (size_t)l * C * ZD, bfv + (size_t)l * C,
            Ws + (size_t)l * C * ZD, bsv + (size_t)l * C, Wc16, bc);
        hipMemcpyAsync(xb, xa, NC * 4, hipMemcpyDeviceToDevice, stream);
        k_edge_mfma<<<NE / 64, 256, 0, stream>>>(xb16, ei, ea, Wc16, bc, xb);

        hipMemsetAsync(colsum, 0, 1024 * 4, stream);
        k_mlp1<<<dim3(NN / 16, HD / 64), 256, 0, stream>>>(xb,
            W1 + (size_t)l * HD * C, b1 + (size_t)l * HD, h, colsum, colsq);
        k_bnstats<<<1, HD, 0, stream>>>(colsum, colsq, mu, istd);

        hipMemsetAsync(gsum, 0, 64 * 4, stream);
        k_mlp2<<<NN / 16, 256, 0, stream>>>(h, mu, istd,
            g1 + (size_t)l * HD, be1 + (size_t)l * HD,
            W2 + (size_t)l * C * HD, b2 + (size_t)l * C, xb, xa);

        k_lnstats<<<(NN + 63) / 64, 256, 0, stream>>>(xa, node_batch, gsum, gsq);
        k_lnfin<<<1, G, 0, stream>>>(gsum, gsq, gcount, gmean, gistd);
        float* dstp = (l == LL - 1) ? out : xa;
        k_lnapply<<<(NN * C) / 256, 256, 0, stream>>>(xa, node_batch, gmean, gistd,
            lnw + (size_t)l * C, lnb + (size_t)l * C, dstp);
    }
}